// Round 3
// baseline (4344.746 us; speedup 1.0000x reference)
//
#include <hip/hip_runtime.h>
#include <cstdint>
#include <cstddef>

static constexpr int T_STEPS = 2048;
static constexpr int BATCH   = 32;
static constexpr int DIM     = 256;
static constexpr int NCOL    = 512;
static constexpr size_t M_ROWS = (size_t)T_STEPS * BATCH;   // 65536

typedef _Float16 f16x2 __attribute__((ext_vector_type(2)));
typedef _Float16 f16x4 __attribute__((ext_vector_type(4)));
typedef _Float16 f16x8 __attribute__((ext_vector_type(8)));
typedef float    f32x4 __attribute__((ext_vector_type(4)));
struct alignas(8) H4 { _Float16 x, y, z, w; };

// ---- workspace layout (bytes) ----
static constexpr size_t XW_OFF   = 0;                           // XW f16 [65536][512] (bias folded) = 64 MB
static constexpr size_t A_OFF    = M_ROWS * NCOL * 2;           // Abuf f16 [65536][256] = 32 MB
static constexpr size_t BLOB_OFF = A_OFF + M_ROWS * DIM * 2;    // 4 blobs x 256 KB
static constexpr size_t BLOB_ELT = (size_t)DIM * NCOL;          // 131072 f16 per blob

// ---------------- prep: f32 -> f16 convert (input) ----------------
__global__ void cvt_f32_to_f16(const float* __restrict__ src, _Float16* __restrict__ dst, int n4) {
  int i = blockIdx.x * blockDim.x + threadIdx.x;
  if (i >= n4) return;
  float4 v = ((const float4*)src)[i];
  H4 o; o.x = (_Float16)v.x; o.y = (_Float16)v.y; o.z = (_Float16)v.z; o.w = (_Float16)v.w;
  ((H4*)dst)[i] = o;
}

// ---------------- prep: W -> MFMA B-fragment blobs (cols 0:512 of [256][768]) ----
// blob[tn][kc][lane][j] = W[kc*32 + (lane>>4)*8 + j][tn*16 + (lane&15)]
__global__ void prep_blobs4(const float* __restrict__ w0, const float* __restrict__ w1,
                            const float* __restrict__ w2, const float* __restrict__ w3,
                            _Float16* __restrict__ blobs) {
  int gid = blockIdx.x * blockDim.x + threadIdx.x;   // < 4*131072
  int mat = gid >> 17;
  int rem = gid & 131071;
  int k = rem >> 9;        // 0..255
  int n = rem & 511;       // 0..511
  const float* src = (mat == 0) ? w0 : (mat == 1) ? w1 : (mat == 2) ? w2 : w3;
  float v = src[k * 768 + n];
  int kc = k >> 5, q = (k >> 3) & 3, j = k & 7, tn = n >> 4;
  int lane = (n & 15) + 16 * q;
  blobs[(size_t)mat * BLOB_ELT + ((size_t)(tn * 8 + kc) * 64 + lane) * 8 + j] = (_Float16)v;
}

// ---------------- GEMM: XW = A[65536,256] @ B[256,512] + bias, row-major f16 ----
__global__ __launch_bounds__(256) void gemm_xw(const _Float16* __restrict__ A,
                                               const _Float16* __restrict__ blob,
                                               const float* __restrict__ bias,
                                               _Float16* __restrict__ XW) {
  int lane = threadIdx.x & 63;
  int wave = threadIdx.x >> 6;
  int wid  = blockIdx.x * 4 + wave;       // 0..8191
  int mbase = (wid >> 1) * 16;
  int nhalf = wid & 1;
  int q = lane >> 4, n15 = lane & 15;

  f32x4 acc[16];
#pragma unroll
  for (int i = 0; i < 16; i++) acc[i] = (f32x4){0.f, 0.f, 0.f, 0.f};

  const _Float16* Arow = A + (size_t)(mbase + n15) * DIM + q * 8;
#pragma unroll
  for (int kc = 0; kc < 8; kc++) {
    f16x8 af = *(const f16x8*)(Arow + kc * 32);
#pragma unroll
    for (int nt = 0; nt < 16; nt++) {
      const _Float16* bp = blob + ((size_t)((nhalf * 16 + nt) * 8 + kc) * 64 + lane) * 8;
      f16x8 bf = *(const f16x8*)bp;
      acc[nt] = __builtin_amdgcn_mfma_f32_16x16x32_f16(af, bf, acc[nt], 0, 0, 0);
    }
  }
#pragma unroll
  for (int nt = 0; nt < 16; nt++) {
    int col = nhalf * 256 + nt * 16 + n15;
    float bv = bias[col];
#pragma unroll
    for (int r = 0; r < 4; r++) {
      int m = mbase + q * 4 + r;
      XW[(size_t)m * NCOL + col] = (_Float16)(acc[nt][r] + bv);
    }
  }
}

// ---------------- recurrence (batch-per-WG MFMA+dot2 hybrid GEMV) ----------------
__device__ __forceinline__ int read_len(const void* p, int b) {
  const long long* q = (const long long*)p;
  bool ok64 = true;
  for (int i = 0; i < 32; i++) { long long v = q[i]; if (v < 0 || v > 2048) ok64 = false; }
  return ok64 ? (int)q[b] : ((const int*)p)[b];
}

// async global->LDS staging of one 1KB xw row (64 lanes x 16B)
__device__ __forceinline__ void gload_lds_row(const _Float16* g, _Float16* l) {
  __builtin_amdgcn_global_load_lds(
      (const __attribute__((address_space(1))) void*)g,
      (__attribute__((address_space(3))) void*)l, 16, 0, 0);
}

// 32 WGs (one batch each), 512 threads = 8 waves, 2 waves/SIMD.
//
// HYBRID step (this round's change): the CU matrix pipe processes ~1 MFMA per
// ~4.85 cy; the old 256 MFMAs/step = ~1240 cy was the step bottleneck (active-CU
// MfmaUtil ~61%). The t-gate columns are moved off the matrix pipe onto the
// VALU via v_dot2_f32_f16:
//   * lane (q,l15)'s A-frag regs hold h[32kc+8q+j]; its Bt[pp][kc] regs hold
//     Whh[32kc+8q+j][tcol] -- exactly matching operands for a per-lane dot
//     over the q-partition of k. 64 fdot2/lane/step, then butterfly-reduce
//     over q (shfl_xor 16, 32).
//   * h-gate columns stay on MFMA: 128 MFMAs/step (~620 cy), overlapping the
//     VALU dot work (separate pipes).
// Everything else keeps the round-2 structure: block-staged xw in LDS dbuf
// (global_load_lds w=16, one vmcnt(0) per 16 steps), raw lgkmcnt(0)+s_barrier
// per step so global stores stay in flight.
template <int LAYER>
__global__ __launch_bounds__(512, 2) void recur(const _Float16* __restrict__ xw,
                                                const _Float16* __restrict__ bblob,
                                                const void* __restrict__ lenp,
                                                _Float16* __restrict__ out0,
                                                float* __restrict__ out1,
                                                float* __restrict__ hn) {
  const int b    = blockIdx.x;             // batch
  const int tid  = threadIdx.x;
  const int w    = tid >> 6;               // wave 0..7
  const int lane = tid & 63;
  const int q = lane >> 4, l15 = lane & 15;
  const int len = read_len(lenp, b);

  // Whh fragments resident in regs: Bh feeds MFMA; Bt feeds VALU fdot2.
  f16x8 Bh[2][8], Bt[2][8];
#pragma unroll
  for (int pp = 0; pp < 2; pp++)
#pragma unroll
    for (int kc = 0; kc < 8; kc++) {
      Bh[pp][kc] = *(const f16x8*)(bblob + ((size_t)((2 * w + pp) * 8 + kc) * 64 + lane) * 8);
      Bt[pp][kc] = *(const f16x8*)(bblob + ((size_t)((16 + 2 * w + pp) * 8 + kc) * 64 + lane) * 8);
    }

  __shared__ __align__(16) _Float16 hbuf[2][DIM];        // ping-pong h (1 KB)
  __shared__ __align__(16) _Float16 xbuf[2][16][NCOL];   // 16-step xw blocks (32 KB)
  if (tid < DIM) hbuf[0][tid] = (_Float16)0.f;

  const int c0 = (2 * w) * 16 + l15;       // h-col of pp=0
  const int c1 = (2 * w + 1) * 16 + l15;   // h-col of pp=1
  const _Float16* xrow = xw + (size_t)b * NCOL;
  const size_t xstride = (size_t)BATCH * NCOL;

  // prologue: stage block 0 (steps 0..15) into xbuf[0]; wave w stages rows 2w,2w+1
  gload_lds_row(xrow + (size_t)(2 * w)     * xstride + lane * 8, &xbuf[0][2 * w][0]);
  gload_lds_row(xrow + (size_t)(2 * w + 1) * xstride + lane * 8, &xbuf[0][2 * w + 1][0]);
  asm volatile("s_waitcnt vmcnt(0)" ::: "memory");
  __syncthreads();

  float h0 = 0.f, h1 = 0.f;                // running h for cols c0, c1 (dup across q)
  const float K1 = 1.442695040888963f, K2 = 2.885390081777927f;

  for (int tb = 0; tb < T_STEPS / 16; ++tb) {
    const int buf = tb & 1;
    // issue staging for the NEXT block immediately; it flies under 16 steps
    // of compute and is only waited on at the block-end vmcnt(0).
    if (tb + 1 < T_STEPS / 16) {
      const _Float16* gsrc = xrow + (size_t)((tb + 1) * 16) * xstride;
      gload_lds_row(gsrc + (size_t)(2 * w)     * xstride + lane * 8, &xbuf[1 - buf][2 * w][0]);
      gload_lds_row(gsrc + (size_t)(2 * w + 1) * xstride + lane * 8, &xbuf[1 - buf][2 * w + 1][0]);
    }
#pragma unroll
    for (int ts = 0; ts < 16; ++ts) {
      const int t = tb * 16 + ts;
      const int p = ts & 1;                // tb*16 is even, so (t&1)==(ts&1)
      // x from LDS (broadcast reads; consumed only in the epilogue)
      const _Float16* xr = &xbuf[buf][ts][0];
      const float xh0 = (float)xr[c0],       xh1 = (float)xr[c1];
      const float xt0 = (float)xr[c0 + 256], xt1 = (float)xr[c1 + 256];

      f32x4 a0 = {0.f, 0.f, 0.f, 0.f}, a1 = a0;
      float t0a[4] = {0.f, 0.f, 0.f, 0.f};
      float t1a[4] = {0.f, 0.f, 0.f, 0.f};
      const _Float16* hb = &hbuf[p][q * 8];
#pragma unroll
      for (int kc = 0; kc < 8; kc++) {
        f16x8 a = *(const f16x8*)(hb + kc * 32);   // broadcast within q-group
        a0 = __builtin_amdgcn_mfma_f32_16x16x32_f16(a, Bh[0][kc], a0, 0, 0, 0);
        a1 = __builtin_amdgcn_mfma_f32_16x16x32_f16(a, Bh[1][kc], a1, 0, 0, 0);
#pragma unroll
        for (int jp = 0; jp < 4; jp++) {
          f16x2 ap = {a[2 * jp], a[2 * jp + 1]};
          f16x2 b0 = {Bt[0][kc][2 * jp], Bt[0][kc][2 * jp + 1]};
          f16x2 b1 = {Bt[1][kc][2 * jp], Bt[1][kc][2 * jp + 1]};
          t0a[jp] = __builtin_amdgcn_fdot2(ap, b0, t0a[jp], false);
          t1a[jp] = __builtin_amdgcn_fdot2(ap, b1, t1a[jp], false);
        }
      }
      // t-gate pre-activations: finish per-lane partials, reduce over q
      float t0 = (t0a[0] + t0a[1]) + (t0a[2] + t0a[3]);
      float t1 = (t1a[0] + t1a[1]) + (t1a[2] + t1a[3]);
      t0 += __shfl_xor(t0, 16, 64);
      t0 += __shfl_xor(t0, 32, 64);
      t1 += __shfl_xor(t1, 16, 64);
      t1 += __shfl_xor(t1, 32, 64);

      const bool live = t < len;
      {
        float ph = a0[0] + xh0, pt = t0 + xt0;
        float phc = fminf(fmaxf(ph, -20.f), 20.f);
        float e1 = __builtin_amdgcn_exp2f(-K2 * phc);
        float e2 = __builtin_amdgcn_exp2f(-K1 * pt);
        float u1 = 1.f + e1;
        float rr = __builtin_amdgcn_rcpf(u1 * (1.f + e2));
        float ttg = (1.f - e1) * rr;
        float tg  = u1 * rr;
        float cg = 0.5f + tg * (0.250905f + tg * (-0.00432f + tg * (-0.015525f)));
        float s = ttg + h0 * cg;
        h0 = live ? s : h0;
      }
      {
        float ph = a1[0] + xh1, pt = t1 + xt1;
        float phc = fminf(fmaxf(ph, -20.f), 20.f);
        float e1 = __builtin_amdgcn_exp2f(-K2 * phc);
        float e2 = __builtin_amdgcn_exp2f(-K1 * pt);
        float u1 = 1.f + e1;
        float rr = __builtin_amdgcn_rcpf(u1 * (1.f + e2));
        float ttg = (1.f - e1) * rr;
        float tg  = u1 * rr;
        float cg = 0.5f + tg * (0.250905f + tg * (-0.00432f + tg * (-0.015525f)));
        float s = ttg + h1 * cg;
        h1 = live ? s : h1;
      }
      _Float16 s0 = (_Float16)h0, s1 = (_Float16)h1;
      if (q == 0) {                           // 16 lanes publish + store
        hbuf[1 - p][c0] = s0;
        hbuf[1 - p][c1] = s1;
        size_t o = ((size_t)t * BATCH + b) * DIM;
        if (LAYER == 0) { out0[o + c0] = s0; out0[o + c1] = s1; }
        else            { out1[o + c0] = h0; out1[o + c1] = h1; }
      }
      if (ts == 15) {
        // block boundary: next block's staging (issued 16 steps ago) must have
        // landed in LDS. Stores also drain here -- once per 16 steps.
        asm volatile("s_waitcnt vmcnt(0) lgkmcnt(0)\n\ts_barrier" ::: "memory");
      } else {
        // order ONLY the LDS h publish; global loads/stores stay in flight
        asm volatile("s_waitcnt lgkmcnt(0)\n\ts_barrier" ::: "memory");
      }
    }
  }

  if (q == 0) {
    hn[LAYER * (BATCH * DIM) + b * DIM + c0] = h0;
    hn[LAYER * (BATCH * DIM) + b * DIM + c1] = h1;
  }
}

extern "C" void kernel_launch(void* const* d_in, const int* in_sizes, int n_in,
                              void* d_out, int out_size, void* d_ws, size_t ws_size,
                              hipStream_t stream) {
  const float* input_ = (const float*)d_in[0];
  const void*  lenp   = d_in[1];
  const float* Wih0   = (const float*)d_in[2];
  const float* Whh0   = (const float*)d_in[3];
  const float* b0     = (const float*)d_in[4];
  const float* Wih1   = (const float*)d_in[5];
  const float* Whh1   = (const float*)d_in[6];
  const float* b1     = (const float*)d_in[7];
  float* out = (float*)d_out;
  char*  ws  = (char*)d_ws;

  _Float16* XW    = (_Float16*)(ws + XW_OFF);
  _Float16* Abuf  = (_Float16*)(ws + A_OFF);
  _Float16* blobs = (_Float16*)(ws + BLOB_OFF);   // [Wih0, Wih1, Whh0, Whh1]
  float* hn = out + M_ROWS * DIM;                 // d_out tail: h_n [2][32][256]

  cvt_f32_to_f16<<<16384, 256, 0, stream>>>(input_, Abuf, (int)(M_ROWS * DIM / 4));
  prep_blobs4<<<2048, 256, 0, stream>>>(Wih0, Wih1, Whh0, Whh1, blobs);
  gemm_xw<<<2048, 256, 0, stream>>>(Abuf, blobs + 0 * BLOB_ELT, b0, XW);
  recur<0><<<BATCH, 512, 0, stream>>>(XW, blobs + 2 * BLOB_ELT, lenp, Abuf, nullptr, hn);
  gemm_xw<<<2048, 256, 0, stream>>>(Abuf, blobs + 1 * BLOB_ELT, b1, XW);
  recur<1><<<BATCH, 512, 0, stream>>>(XW, blobs + 3 * BLOB_ELT, lenp, nullptr, out, hn);
}

// Round 4
// 2525.482 us; speedup vs baseline: 1.7204x; 1.7204x over previous
//
#include <hip/hip_runtime.h>
#include <cstdint>
#include <cstddef>

static constexpr int T_STEPS = 2048;
static constexpr int BATCH   = 32;
static constexpr int DIM     = 256;
static constexpr int NCOL    = 512;
static constexpr size_t M_ROWS = (size_t)T_STEPS * BATCH;   // 65536

typedef _Float16 f16x4 __attribute__((ext_vector_type(4)));
typedef _Float16 f16x8 __attribute__((ext_vector_type(8)));
typedef float    f32x4 __attribute__((ext_vector_type(4)));
struct alignas(8) H4 { _Float16 x, y, z, w; };

// ---- workspace layout (bytes) ----
static constexpr size_t XW_OFF   = 0;                           // XW f16 [65536][512] (bias folded) = 64 MB
static constexpr size_t A_OFF    = M_ROWS * NCOL * 2;           // Abuf f16 [65536][256] = 32 MB
static constexpr size_t BLOB_OFF = A_OFF + M_ROWS * DIM * 2;    // 4 blobs x 256 KB
static constexpr size_t BLOB_ELT = (size_t)DIM * NCOL;          // 131072 f16 per blob
static constexpr size_t FLAG_OFF = BLOB_OFF + 4 * BLOB_ELT * 2; // int[32] progress flags

// ---------------- prep: f32 -> f16 convert (input) + flag zero ----------------
__global__ void cvt_f32_to_f16(const float* __restrict__ src, _Float16* __restrict__ dst,
                               int n4, int* __restrict__ flags) {
  if (blockIdx.x == 0 && threadIdx.x < BATCH) flags[threadIdx.x] = 0;
  int i = blockIdx.x * blockDim.x + threadIdx.x;
  if (i >= n4) return;
  float4 v = ((const float4*)src)[i];
  H4 o; o.x = (_Float16)v.x; o.y = (_Float16)v.y; o.z = (_Float16)v.z; o.w = (_Float16)v.w;
  ((H4*)dst)[i] = o;
}

// ---------------- prep: W -> MFMA B-fragment blobs (cols 0:512 of [256][768]) ----
// blob[tn][kc][lane][j] = W[kc*32 + (lane>>4)*8 + j][tn*16 + (lane&15)]
__global__ void prep_blobs4(const float* __restrict__ w0, const float* __restrict__ w1,
                            const float* __restrict__ w2, const float* __restrict__ w3,
                            _Float16* __restrict__ blobs) {
  int gid = blockIdx.x * blockDim.x + threadIdx.x;   // < 4*131072
  int mat = gid >> 17;
  int rem = gid & 131071;
  int k = rem >> 9;        // 0..255
  int n = rem & 511;       // 0..511
  const float* src = (mat == 0) ? w0 : (mat == 1) ? w1 : (mat == 2) ? w2 : w3;
  float v = src[k * 768 + n];
  int kc = k >> 5, q = (k >> 3) & 3, j = k & 7, tn = n >> 4;
  int lane = (n & 15) + 16 * q;
  blobs[(size_t)mat * BLOB_ELT + ((size_t)(tn * 8 + kc) * 64 + lane) * 8 + j] = (_Float16)v;
}

// ---------------- GEMM: XW = A[65536,256] @ B[256,512] + bias, row-major f16 ----
__global__ __launch_bounds__(256) void gemm_xw(const _Float16* __restrict__ A,
                                               const _Float16* __restrict__ blob,
                                               const float* __restrict__ bias,
                                               _Float16* __restrict__ XW) {
  int lane = threadIdx.x & 63;
  int wave = threadIdx.x >> 6;
  int wid  = blockIdx.x * 4 + wave;       // 0..8191
  int mbase = (wid >> 1) * 16;
  int nhalf = wid & 1;
  int q = lane >> 4, n15 = lane & 15;

  f32x4 acc[16];
#pragma unroll
  for (int i = 0; i < 16; i++) acc[i] = (f32x4){0.f, 0.f, 0.f, 0.f};

  const _Float16* Arow = A + (size_t)(mbase + n15) * DIM + q * 8;
#pragma unroll
  for (int kc = 0; kc < 8; kc++) {
    f16x8 af = *(const f16x8*)(Arow + kc * 32);
#pragma unroll
    for (int nt = 0; nt < 16; nt++) {
      const _Float16* bp = blob + ((size_t)((nhalf * 16 + nt) * 8 + kc) * 64 + lane) * 8;
      f16x8 bf = *(const f16x8*)bp;
      acc[nt] = __builtin_amdgcn_mfma_f32_16x16x32_f16(af, bf, acc[nt], 0, 0, 0);
    }
  }
#pragma unroll
  for (int nt = 0; nt < 16; nt++) {
    int col = nhalf * 256 + nt * 16 + n15;
    float bv = bias[col];
#pragma unroll
    for (int r = 0; r < 4; r++) {
      int m = mbase + q * 4 + r;
      XW[(size_t)m * NCOL + col] = (_Float16)(acc[nt][r] + bv);
    }
  }
}

// ---------------- fused two-layer recurrence (producer/consumer pipeline) ----------------
__device__ __forceinline__ int read_len(const void* p, int b) {
  const long long* q = (const long long*)p;
  bool ok64 = true;
  for (int i = 0; i < 32; i++) { long long v = q[i]; if (v < 0 || v > 2048) ok64 = false; }
  return ok64 ? (int)q[b] : ((const int*)p)[b];
}

// async global->LDS staging of one 1KB xw row (64 lanes x 16B)
__device__ __forceinline__ void gload_lds_row(const _Float16* g, _Float16* l) {
  __builtin_amdgcn_global_load_lds(
      (const __attribute__((address_space(1))) void*)g,
      (__attribute__((address_space(3))) void*)l, 16, 0, 0);
}

// Shared per-step epilogue math (bug-faithful gate computation).
__device__ __forceinline__ void gate_update(float pre_h, float pre_t, bool live, float& h) {
  const float K1 = 1.442695040888963f, K2 = 2.885390081777927f;
  float phc = fminf(fmaxf(pre_h, -20.f), 20.f);
  float e1 = __builtin_amdgcn_exp2f(-K2 * phc);
  float e2 = __builtin_amdgcn_exp2f(-K1 * pre_t);
  float u1 = 1.f + e1;
  float rr = __builtin_amdgcn_rcpf(u1 * (1.f + e2));
  float ttg = (1.f - e1) * rr;
  float tg  = u1 * rr;
  float cg = 0.5f + tg * (0.250905f + tg * (-0.00432f + tg * (-0.015525f)));
  float s = ttg + h * cg;
  h = live ? s : h;
}

// 64 WGs, 512 threads each (8 waves, ~1 WG/CU with 64<=256 CUs).
//  * WG b in [0,32): PRODUCER = layer-0 recurrence, identical to the verified
//    round-2 structure (block-staged xw0 from HBM, raw lgkmcnt barriers,
//    vmcnt(0) once per 16-step block). After each block's vmcnt(0)+barrier it
//    publishes flags[b]=tb+1 with agent-scope RELEASE (writes back L2).
//  * WG 32+b: CONSUMER = layer-1 recurrence. Per 16-step block: acquire-poll
//    flags[b] > tb, then compute this block's xw1 = out0[16 rows] @ Wih1 + b1
//    as a DENSE M=16 MFMA GEMM (rows = timesteps; 256 MFMAs/block = ~78cy/step
//    amortized vs 256/step for the M=1 GEMV), write to LDS, then run 16 steps.
// Deadlock-free: 64 WGs <= 256 CUs -> all resident regardless of dispatch
// order; producers never wait on consumers.
__global__ __launch_bounds__(512, 2) void recur_fused(const _Float16* __restrict__ xw0,
                                                      const _Float16* __restrict__ bwhh0,
                                                      const _Float16* __restrict__ bwhh1,
                                                      const _Float16* __restrict__ bwih1,
                                                      const float* __restrict__ b1,
                                                      const void* __restrict__ lenp,
                                                      _Float16* __restrict__ out0,
                                                      float* __restrict__ out1,
                                                      float* __restrict__ hn,
                                                      int* __restrict__ flags) {
  const int bid  = blockIdx.x;
  const int tid  = threadIdx.x;
  const int w    = tid >> 6;               // wave 0..7
  const int lane = tid & 63;
  const int q = lane >> 4, l15 = lane & 15;

  __shared__ __align__(16) _Float16 hbuf[2][DIM];        // ping-pong h (1 KB)
  __shared__ __align__(16) _Float16 xbuf[2][16][NCOL];   // xw blocks (32 KB)

  const int c0 = (2 * w) * 16 + l15;
  const int c1 = (2 * w + 1) * 16 + l15;

  if (bid < BATCH) {
    // ================= PRODUCER: layer 0 =================
    const int b = bid;
    const int len = read_len(lenp, b);
    f16x8 Bh[2][8], Bt[2][8];
#pragma unroll
    for (int pp = 0; pp < 2; pp++)
#pragma unroll
      for (int kc = 0; kc < 8; kc++) {
        Bh[pp][kc] = *(const f16x8*)(bwhh0 + ((size_t)((2 * w + pp) * 8 + kc) * 64 + lane) * 8);
        Bt[pp][kc] = *(const f16x8*)(bwhh0 + ((size_t)((16 + 2 * w + pp) * 8 + kc) * 64 + lane) * 8);
      }
    if (tid < DIM) hbuf[0][tid] = (_Float16)0.f;

    const _Float16* xrow = xw0 + (size_t)b * NCOL;
    const size_t xstride = (size_t)BATCH * NCOL;

    gload_lds_row(xrow + (size_t)(2 * w)     * xstride + lane * 8, &xbuf[0][2 * w][0]);
    gload_lds_row(xrow + (size_t)(2 * w + 1) * xstride + lane * 8, &xbuf[0][2 * w + 1][0]);
    asm volatile("s_waitcnt vmcnt(0)" ::: "memory");
    __syncthreads();

    float h0 = 0.f, h1 = 0.f;
    for (int tb = 0; tb < T_STEPS / 16; ++tb) {
      const int buf = tb & 1;
      if (tb + 1 < T_STEPS / 16) {
        const _Float16* gsrc = xrow + (size_t)((tb + 1) * 16) * xstride;
        gload_lds_row(gsrc + (size_t)(2 * w)     * xstride + lane * 8, &xbuf[1 - buf][2 * w][0]);
        gload_lds_row(gsrc + (size_t)(2 * w + 1) * xstride + lane * 8, &xbuf[1 - buf][2 * w + 1][0]);
      }
#pragma unroll
      for (int ts = 0; ts < 16; ++ts) {
        const int t = tb * 16 + ts;
        const int p = ts & 1;
        const _Float16* xr = &xbuf[buf][ts][0];
        const float xh0 = (float)xr[c0],       xh1 = (float)xr[c1];
        const float xt0 = (float)xr[c0 + 256], xt1 = (float)xr[c1 + 256];

        f32x4 a0 = {0.f, 0.f, 0.f, 0.f}, a1 = a0, a2 = a0, a3 = a0;
        const _Float16* hb = &hbuf[p][q * 8];
#pragma unroll
        for (int kc = 0; kc < 8; kc++) {
          f16x8 a = *(const f16x8*)(hb + kc * 32);
          a0 = __builtin_amdgcn_mfma_f32_16x16x32_f16(a, Bh[0][kc], a0, 0, 0, 0);
          a1 = __builtin_amdgcn_mfma_f32_16x16x32_f16(a, Bh[1][kc], a1, 0, 0, 0);
          a2 = __builtin_amdgcn_mfma_f32_16x16x32_f16(a, Bt[0][kc], a2, 0, 0, 0);
          a3 = __builtin_amdgcn_mfma_f32_16x16x32_f16(a, Bt[1][kc], a3, 0, 0, 0);
        }
        const bool live = t < len;
        gate_update(a0[0] + xh0, a2[0] + xt0, live, h0);
        gate_update(a1[0] + xh1, a3[0] + xt1, live, h1);
        _Float16 s0 = (_Float16)h0, s1 = (_Float16)h1;
        if (q == 0) {
          hbuf[1 - p][c0] = s0;
          hbuf[1 - p][c1] = s1;
          size_t o = ((size_t)t * BATCH + b) * DIM;
          out0[o + c0] = s0; out0[o + c1] = s1;
        }
        if (ts == 15) {
          asm volatile("s_waitcnt vmcnt(0) lgkmcnt(0)\n\ts_barrier" ::: "memory");
        } else {
          asm volatile("s_waitcnt lgkmcnt(0)\n\ts_barrier" ::: "memory");
        }
      }
      // all waves' out0 stores for blocks <= tb have drained (per-wave vmcnt(0)
      // before the barrier). Release writes back L2 -> device-visible.
      if (tid == 0)
        __hip_atomic_store(&flags[b], tb + 1, __ATOMIC_RELEASE, __HIP_MEMORY_SCOPE_AGENT);
    }
    if (q == 0) {
      hn[b * DIM + c0] = h0;
      hn[b * DIM + c1] = h1;
    }
  } else {
    // ================= CONSUMER: layer 1 =================
    const int b = bid - BATCH;
    const int len = read_len(lenp, b);
    f16x8 Bh[2][8], Bt[2][8];
#pragma unroll
    for (int pp = 0; pp < 2; pp++)
#pragma unroll
      for (int kc = 0; kc < 8; kc++) {
        Bh[pp][kc] = *(const f16x8*)(bwhh1 + ((size_t)((2 * w + pp) * 8 + kc) * 64 + lane) * 8);
        Bt[pp][kc] = *(const f16x8*)(bwhh1 + ((size_t)((16 + 2 * w + pp) * 8 + kc) * 64 + lane) * 8);
      }
    const float bb0 = b1[c0], bb1 = b1[c1], bb2 = b1[c0 + 256], bb3 = b1[c1 + 256];
    if (tid < DIM) hbuf[0][tid] = (_Float16)0.f;
    __syncthreads();

    float h0 = 0.f, h1 = 0.f;
    for (int tb = 0; tb < T_STEPS / 16; ++tb) {
      // ---- wait for producer block tb ----
      if (tid == 0) {
        int it = 0;
        while (__hip_atomic_load(&flags[b], __ATOMIC_RELAXED, __HIP_MEMORY_SCOPE_AGENT) <= tb) {
          __builtin_amdgcn_s_sleep(2);
          if (++it > (1 << 20)) break;   // hang-breaker: fail loud, not forever
        }
        (void)__hip_atomic_load(&flags[b], __ATOMIC_ACQUIRE, __HIP_MEMORY_SCOPE_AGENT);
      }
      __syncthreads();

      // ---- dense x-GEMM: xw1[16 steps][my 64 cols] = out0 @ Wih1 + b1 ----
      const int t0 = tb * 16;
      const _Float16* arow = out0 + ((size_t)(t0 + l15) * BATCH + b) * DIM + q * 8;
      f16x8 xa[8];
#pragma unroll
      for (int kc = 0; kc < 8; kc++) xa[kc] = *(const f16x8*)(arow + kc * 32);
#pragma unroll
      for (int ti = 0; ti < 4; ti++) {
        const int tn  = (ti < 2) ? (2 * w + ti) : (16 + 2 * w + (ti - 2));
        f32x4 acc = {0.f, 0.f, 0.f, 0.f};
#pragma unroll
        for (int kc = 0; kc < 8; kc++) {
          f16x8 bf = *(const f16x8*)(bwih1 + ((size_t)(tn * 8 + kc) * 64 + lane) * 8);
          acc = __builtin_amdgcn_mfma_f32_16x16x32_f16(xa[kc], bf, acc, 0, 0, 0);
        }
        const int   col = (ti == 0) ? c0 : (ti == 1) ? c1 : (ti == 2) ? (c0 + 256) : (c1 + 256);
        const float bv  = (ti == 0) ? bb0 : (ti == 1) ? bb1 : (ti == 2) ? bb2 : bb3;
#pragma unroll
        for (int r = 0; r < 4; r++) xbuf[0][q * 4 + r][col] = (_Float16)(acc[r] + bv);
      }
      asm volatile("s_waitcnt lgkmcnt(0)\n\ts_barrier" ::: "memory");

      // ---- 16 recurrence steps ----
#pragma unroll
      for (int ts = 0; ts < 16; ++ts) {
        const int t = t0 + ts;
        const int p = ts & 1;
        const _Float16* xr = &xbuf[0][ts][0];
        const float xh0 = (float)xr[c0],       xh1 = (float)xr[c1];
        const float xt0 = (float)xr[c0 + 256], xt1 = (float)xr[c1 + 256];

        f32x4 a0 = {0.f, 0.f, 0.f, 0.f}, a1 = a0, a2 = a0, a3 = a0;
        const _Float16* hb = &hbuf[p][q * 8];
#pragma unroll
        for (int kc = 0; kc < 8; kc++) {
          f16x8 a = *(const f16x8*)(hb + kc * 32);
          a0 = __builtin_amdgcn_mfma_f32_16x16x32_f16(a, Bh[0][kc], a0, 0, 0, 0);
          a1 = __builtin_amdgcn_mfma_f32_16x16x32_f16(a, Bh[1][kc], a1, 0, 0, 0);
          a2 = __builtin_amdgcn_mfma_f32_16x16x32_f16(a, Bt[0][kc], a2, 0, 0, 0);
          a3 = __builtin_amdgcn_mfma_f32_16x16x32_f16(a, Bt[1][kc], a3, 0, 0, 0);
        }
        const bool live = t < len;
        gate_update(a0[0] + xh0, a2[0] + xt0, live, h0);
        gate_update(a1[0] + xh1, a3[0] + xt1, live, h1);
        if (q == 0) {
          hbuf[1 - p][c0] = (_Float16)h0;
          hbuf[1 - p][c1] = (_Float16)h1;
          size_t o = ((size_t)t * BATCH + b) * DIM;
          out1[o + c0] = h0; out1[o + c1] = h1;
        }
        asm volatile("s_waitcnt lgkmcnt(0)\n\ts_barrier" ::: "memory");
      }
    }
    if (q == 0) {
      hn[BATCH * DIM + b * DIM + c0] = h0;
      hn[BATCH * DIM + b * DIM + c1] = h1;
    }
  }
}

extern "C" void kernel_launch(void* const* d_in, const int* in_sizes, int n_in,
                              void* d_out, int out_size, void* d_ws, size_t ws_size,
                              hipStream_t stream) {
  const float* input_ = (const float*)d_in[0];
  const void*  lenp   = d_in[1];
  const float* Wih0   = (const float*)d_in[2];
  const float* Whh0   = (const float*)d_in[3];
  const float* b0     = (const float*)d_in[4];
  const float* Wih1   = (const float*)d_in[5];
  const float* Whh1   = (const float*)d_in[6];
  const float* b1     = (const float*)d_in[7];
  float* out = (float*)d_out;
  char*  ws  = (char*)d_ws;

  _Float16* XW    = (_Float16*)(ws + XW_OFF);
  _Float16* Abuf  = (_Float16*)(ws + A_OFF);
  _Float16* blobs = (_Float16*)(ws + BLOB_OFF);   // [Wih0, Wih1, Whh0, Whh1]
  int*      flags = (int*)(ws + FLAG_OFF);
  float* hn = out + M_ROWS * DIM;                 // d_out tail: h_n [2][32][256]

  cvt_f32_to_f16<<<16384, 256, 0, stream>>>(input_, Abuf, (int)(M_ROWS * DIM / 4), flags);
  prep_blobs4<<<2048, 256, 0, stream>>>(Wih0, Wih1, Whh0, Whh1, blobs);
  gemm_xw<<<2048, 256, 0, stream>>>(Abuf, blobs + 0 * BLOB_ELT, b0, XW);
  recur_fused<<<2 * BATCH, 512, 0, stream>>>(XW,
                                             blobs + 2 * BLOB_ELT,   // Whh0 blob
                                             blobs + 3 * BLOB_ELT,   // Whh1 blob
                                             blobs + 1 * BLOB_ELT,   // Wih1 blob
                                             b1, lenp, Abuf, out, hn, flags);
}

// Round 5
// 2495.008 us; speedup vs baseline: 1.7414x; 1.0122x over previous
//
#include <hip/hip_runtime.h>
#include <cstdint>
#include <cstddef>

static constexpr int T_STEPS = 2048;
static constexpr int BATCH   = 32;
static constexpr int DIM     = 256;
static constexpr int NCOL    = 512;
static constexpr size_t M_ROWS = (size_t)T_STEPS * BATCH;   // 65536

typedef _Float16 f16x4 __attribute__((ext_vector_type(4)));
typedef _Float16 f16x8 __attribute__((ext_vector_type(8)));
typedef float    f32x4 __attribute__((ext_vector_type(4)));
struct alignas(8) H4 { _Float16 x, y, z, w; };

// ---- workspace layout (bytes) ----
static constexpr size_t XW_OFF   = 0;                           // XW f16 [65536][512] (bias folded) = 64 MB
static constexpr size_t A_OFF    = M_ROWS * NCOL * 2;           // Abuf f16 [65536][256] = 32 MB
static constexpr size_t BLOB_OFF = A_OFF + M_ROWS * DIM * 2;    // 4 blobs x 256 KB
static constexpr size_t BLOB_ELT = (size_t)DIM * NCOL;          // 131072 f16 per blob
static constexpr size_t FLAG_OFF = BLOB_OFF + 4 * BLOB_ELT * 2; // int[32] progress flags

// ---------------- prep: f32 -> f16 convert (input) + flag zero ----------------
__global__ void cvt_f32_to_f16(const float* __restrict__ src, _Float16* __restrict__ dst,
                               int n4, int* __restrict__ flags) {
  if (blockIdx.x == 0 && threadIdx.x < BATCH) flags[threadIdx.x] = 0;
  int i = blockIdx.x * blockDim.x + threadIdx.x;
  if (i >= n4) return;
  float4 v = ((const float4*)src)[i];
  H4 o; o.x = (_Float16)v.x; o.y = (_Float16)v.y; o.z = (_Float16)v.z; o.w = (_Float16)v.w;
  ((H4*)dst)[i] = o;
}

// ---------------- prep: W -> MFMA B-fragment blobs (cols 0:512 of [256][768]) ----
// blob[tn][kc][lane][j] = W[kc*32 + (lane>>4)*8 + j][tn*16 + (lane&15)]
__global__ void prep_blobs4(const float* __restrict__ w0, const float* __restrict__ w1,
                            const float* __restrict__ w2, const float* __restrict__ w3,
                            _Float16* __restrict__ blobs) {
  int gid = blockIdx.x * blockDim.x + threadIdx.x;   // < 4*131072
  int mat = gid >> 17;
  int rem = gid & 131071;
  int k = rem >> 9;        // 0..255
  int n = rem & 511;       // 0..511
  const float* src = (mat == 0) ? w0 : (mat == 1) ? w1 : (mat == 2) ? w2 : w3;
  float v = src[k * 768 + n];
  int kc = k >> 5, q = (k >> 3) & 3, j = k & 7, tn = n >> 4;
  int lane = (n & 15) + 16 * q;
  blobs[(size_t)mat * BLOB_ELT + ((size_t)(tn * 8 + kc) * 64 + lane) * 8 + j] = (_Float16)v;
}

// ---------------- GEMM: XW = A[65536,256] @ B[256,512] + bias, row-major f16 ----
__global__ __launch_bounds__(256) void gemm_xw(const _Float16* __restrict__ A,
                                               const _Float16* __restrict__ blob,
                                               const float* __restrict__ bias,
                                               _Float16* __restrict__ XW) {
  int lane = threadIdx.x & 63;
  int wave = threadIdx.x >> 6;
  int wid  = blockIdx.x * 4 + wave;       // 0..8191
  int mbase = (wid >> 1) * 16;
  int nhalf = wid & 1;
  int q = lane >> 4, n15 = lane & 15;

  f32x4 acc[16];
#pragma unroll
  for (int i = 0; i < 16; i++) acc[i] = (f32x4){0.f, 0.f, 0.f, 0.f};

  const _Float16* Arow = A + (size_t)(mbase + n15) * DIM + q * 8;
#pragma unroll
  for (int kc = 0; kc < 8; kc++) {
    f16x8 af = *(const f16x8*)(Arow + kc * 32);
#pragma unroll
    for (int nt = 0; nt < 16; nt++) {
      const _Float16* bp = blob + ((size_t)((nhalf * 16 + nt) * 8 + kc) * 64 + lane) * 8;
      f16x8 bf = *(const f16x8*)bp;
      acc[nt] = __builtin_amdgcn_mfma_f32_16x16x32_f16(af, bf, acc[nt], 0, 0, 0);
    }
  }
#pragma unroll
  for (int nt = 0; nt < 16; nt++) {
    int col = nhalf * 256 + nt * 16 + n15;
    float bv = bias[col];
#pragma unroll
    for (int r = 0; r < 4; r++) {
      int m = mbase + q * 4 + r;
      XW[(size_t)m * NCOL + col] = (_Float16)(acc[nt][r] + bv);
    }
  }
}

// ---------------- fused two-layer recurrence (producer/consumer pipeline) ----------------
__device__ __forceinline__ int read_len(const void* p, int b) {
  const long long* q = (const long long*)p;
  bool ok64 = true;
  for (int i = 0; i < 32; i++) { long long v = q[i]; if (v < 0 || v > 2048) ok64 = false; }
  return ok64 ? (int)q[b] : ((const int*)p)[b];
}

// async global->LDS staging of one 1KB xw row (64 lanes x 16B)
__device__ __forceinline__ void gload_lds_row(const _Float16* g, _Float16* l) {
  __builtin_amdgcn_global_load_lds(
      (const __attribute__((address_space(1))) void*)g,
      (__attribute__((address_space(3))) void*)l, 16, 0, 0);
}

// Shared per-step epilogue math (bug-faithful gate computation).
__device__ __forceinline__ void gate_update(float pre_h, float pre_t, bool live, float& h) {
  const float K1 = 1.442695040888963f, K2 = 2.885390081777927f;
  float phc = fminf(fmaxf(pre_h, -20.f), 20.f);
  float e1 = __builtin_amdgcn_exp2f(-K2 * phc);
  float e2 = __builtin_amdgcn_exp2f(-K1 * pre_t);
  float u1 = 1.f + e1;
  float rr = __builtin_amdgcn_rcpf(u1 * (1.f + e2));
  float ttg = (1.f - e1) * rr;
  float tg  = u1 * rr;
  float cg = 0.5f + tg * (0.250905f + tg * (-0.00432f + tg * (-0.015525f)));
  float s = ttg + h * cg;
  h = live ? s : h;
}

// 64 WGs, 512 threads each (8 waves, ~1 WG/CU with 64<=256 CUs).
//  * WG b in [0,32): PRODUCER = layer-0 recurrence (round-2 verified structure):
//    block-staged xw0, raw lgkmcnt barriers, vmcnt(0) once per 16-step block,
//    then agent-scope RELEASE flags[b]=tb+1 (writes back L2 -> device-visible).
//  * WG 32+b: CONSUMER = layer-1 recurrence, software-pipelined (T14 split):
//    iteration tb: {poll flag>=tb+2, ISSUE out0-block-(tb+1) loads into regs}
//    -> 16 recurrence steps of block tb (loads fly underneath, ~27k cy cover)
//    -> dense M=16 x-GEMM for block tb+1 from regs (pure MFMA, ~1240 cy)
//    -> ds_write + barrier. Global-load latency and poll are OFF the critical
//    path; only ~78 cy/step of extra MFMA remains on it.
// Deadlock-free: 64 WGs <= 256 CUs -> all resident; producers never wait.
__global__ __launch_bounds__(512, 2) void recur_fused(const _Float16* __restrict__ xw0,
                                                      const _Float16* __restrict__ bwhh0,
                                                      const _Float16* __restrict__ bwhh1,
                                                      const _Float16* __restrict__ bwih1,
                                                      const float* __restrict__ b1,
                                                      const void* __restrict__ lenp,
                                                      _Float16* __restrict__ out0,
                                                      float* __restrict__ out1,
                                                      float* __restrict__ hn,
                                                      int* __restrict__ flags) {
  const int bid  = blockIdx.x;
  const int tid  = threadIdx.x;
  const int w    = tid >> 6;               // wave 0..7
  const int lane = tid & 63;
  const int q = lane >> 4, l15 = lane & 15;

  __shared__ __align__(16) _Float16 hbuf[2][DIM];        // ping-pong h (1 KB)
  __shared__ __align__(16) _Float16 xbuf[2][16][NCOL];   // xw blocks (32 KB)

  const int c0 = (2 * w) * 16 + l15;
  const int c1 = (2 * w + 1) * 16 + l15;
  constexpr int NB = T_STEPS / 16;

  if (bid < BATCH) {
    // ================= PRODUCER: layer 0 =================
    const int b = bid;
    const int len = read_len(lenp, b);
    f16x8 Bh[2][8], Bt[2][8];
#pragma unroll
    for (int pp = 0; pp < 2; pp++)
#pragma unroll
      for (int kc = 0; kc < 8; kc++) {
        Bh[pp][kc] = *(const f16x8*)(bwhh0 + ((size_t)((2 * w + pp) * 8 + kc) * 64 + lane) * 8);
        Bt[pp][kc] = *(const f16x8*)(bwhh0 + ((size_t)((16 + 2 * w + pp) * 8 + kc) * 64 + lane) * 8);
      }
    if (tid < DIM) hbuf[0][tid] = (_Float16)0.f;

    const _Float16* xrow = xw0 + (size_t)b * NCOL;
    const size_t xstride = (size_t)BATCH * NCOL;

    gload_lds_row(xrow + (size_t)(2 * w)     * xstride + lane * 8, &xbuf[0][2 * w][0]);
    gload_lds_row(xrow + (size_t)(2 * w + 1) * xstride + lane * 8, &xbuf[0][2 * w + 1][0]);
    asm volatile("s_waitcnt vmcnt(0)" ::: "memory");
    __syncthreads();

    float h0 = 0.f, h1 = 0.f;
    for (int tb = 0; tb < NB; ++tb) {
      const int buf = tb & 1;
      if (tb + 1 < NB) {
        const _Float16* gsrc = xrow + (size_t)((tb + 1) * 16) * xstride;
        gload_lds_row(gsrc + (size_t)(2 * w)     * xstride + lane * 8, &xbuf[1 - buf][2 * w][0]);
        gload_lds_row(gsrc + (size_t)(2 * w + 1) * xstride + lane * 8, &xbuf[1 - buf][2 * w + 1][0]);
      }
#pragma unroll
      for (int ts = 0; ts < 16; ++ts) {
        const int t = tb * 16 + ts;
        const int p = ts & 1;
        const _Float16* xr = &xbuf[buf][ts][0];
        const float xh0 = (float)xr[c0],       xh1 = (float)xr[c1];
        const float xt0 = (float)xr[c0 + 256], xt1 = (float)xr[c1 + 256];

        f32x4 a0 = {0.f, 0.f, 0.f, 0.f}, a1 = a0, a2 = a0, a3 = a0;
        const _Float16* hb = &hbuf[p][q * 8];
#pragma unroll
        for (int kc = 0; kc < 8; kc++) {
          f16x8 a = *(const f16x8*)(hb + kc * 32);
          a0 = __builtin_amdgcn_mfma_f32_16x16x32_f16(a, Bh[0][kc], a0, 0, 0, 0);
          a1 = __builtin_amdgcn_mfma_f32_16x16x32_f16(a, Bh[1][kc], a1, 0, 0, 0);
          a2 = __builtin_amdgcn_mfma_f32_16x16x32_f16(a, Bt[0][kc], a2, 0, 0, 0);
          a3 = __builtin_amdgcn_mfma_f32_16x16x32_f16(a, Bt[1][kc], a3, 0, 0, 0);
        }
        const bool live = t < len;
        gate_update(a0[0] + xh0, a2[0] + xt0, live, h0);
        gate_update(a1[0] + xh1, a3[0] + xt1, live, h1);
        _Float16 s0 = (_Float16)h0, s1 = (_Float16)h1;
        if (q == 0) {
          hbuf[1 - p][c0] = s0;
          hbuf[1 - p][c1] = s1;
          size_t o = ((size_t)t * BATCH + b) * DIM;
          out0[o + c0] = s0; out0[o + c1] = s1;
        }
        if (ts == 15) {
          // every wave drains its own out0 stores + staging loads, then syncs.
          asm volatile("s_waitcnt vmcnt(0) lgkmcnt(0)\n\ts_barrier" ::: "memory");
        } else {
          asm volatile("s_waitcnt lgkmcnt(0)\n\ts_barrier" ::: "memory");
        }
      }
      // all waves' out0 stores for blocks <= tb are L2-acked; release writes
      // back L2 -> device-visible, then publishes the flag.
      if (tid == 0)
        __hip_atomic_store(&flags[b], tb + 1, __ATOMIC_RELEASE, __HIP_MEMORY_SCOPE_AGENT);
    }
    if (q == 0) {
      hn[b * DIM + c0] = h0;
      hn[b * DIM + c1] = h1;
    }
  } else {
    // ================= CONSUMER: layer 1 (software-pipelined) =================
    const int b = bid - BATCH;
    const int len = read_len(lenp, b);
    f16x8 Bh[2][8], Bt[2][8];
#pragma unroll
    for (int pp = 0; pp < 2; pp++)
#pragma unroll
      for (int kc = 0; kc < 8; kc++) {
        Bh[pp][kc] = *(const f16x8*)(bwhh1 + ((size_t)((2 * w + pp) * 8 + kc) * 64 + lane) * 8);
        Bt[pp][kc] = *(const f16x8*)(bwhh1 + ((size_t)((16 + 2 * w + pp) * 8 + kc) * 64 + lane) * 8);
      }
    const float bb0 = b1[c0], bb1 = b1[c1], bb2 = b1[c0 + 256], bb3 = b1[c1 + 256];
    if (tid < DIM) hbuf[0][tid] = (_Float16)0.f;
    __syncthreads();

    // whole-wave flag wait: all 64 lanes poll the same address (one memop/
    // iteration, broadcast); acquire load pulls coherent data after.
#define WAIT_FLAG(TH_)                                                                   \
    {                                                                                    \
      int it = 0;                                                                        \
      while (__hip_atomic_load(&flags[b], __ATOMIC_RELAXED, __HIP_MEMORY_SCOPE_AGENT)    \
             < (TH_)) {                                                                  \
        __builtin_amdgcn_s_sleep(2);                                                     \
        if (++it > (1 << 22)) break;   /* hang-breaker: fail loud, not forever */        \
      }                                                                                  \
      (void)__hip_atomic_load(&flags[b], __ATOMIC_ACQUIRE, __HIP_MEMORY_SCOPE_AGENT);    \
    }

    // dense x-GEMM from registers XA_ into xbuf[DST_]: rows = 16 timesteps,
    // my 64 cols (c0, c1, +256 pairs). Pure MFMA + ds_write.
#define XGEMM(XA_, DST_)                                                                 \
    {                                                                                    \
      _Pragma("unroll")                                                                  \
      for (int ti = 0; ti < 4; ti++) {                                                   \
        const int tn = (ti < 2) ? (2 * w + ti) : (16 + 2 * w + (ti - 2));                \
        f32x4 acc = {0.f, 0.f, 0.f, 0.f};                                                \
        _Pragma("unroll")                                                                \
        for (int kc = 0; kc < 8; kc++) {                                                 \
          f16x8 bf = *(const f16x8*)(bwih1 + ((size_t)(tn * 8 + kc) * 64 + lane) * 8);   \
          acc = __builtin_amdgcn_mfma_f32_16x16x32_f16(XA_[kc], bf, acc, 0, 0, 0);       \
        }                                                                                \
        const int   col = (ti == 0) ? c0 : (ti == 1) ? c1 : (ti == 2) ? (c0 + 256)       \
                                                                      : (c1 + 256);      \
        const float bv  = (ti == 0) ? bb0 : (ti == 1) ? bb1 : (ti == 2) ? bb2 : bb3;     \
        _Pragma("unroll")                                                                \
        for (int r = 0; r < 4; r++) xbuf[DST_][q * 4 + r][col] = (_Float16)(acc[r] + bv);\
      }                                                                                  \
    }

    float h0 = 0.f, h1 = 0.f;

    // prologue: xw1 for block 0 (serial once; off steady-state path)
    WAIT_FLAG(1);
    {
      const _Float16* arow = out0 + ((size_t)l15 * BATCH + b) * DIM + q * 8;
      f16x8 xa0[8];
#pragma unroll
      for (int kc = 0; kc < 8; kc++) xa0[kc] = *(const f16x8*)(arow + kc * 32);
      XGEMM(xa0, 0);
    }
    asm volatile("s_waitcnt lgkmcnt(0)\n\ts_barrier" ::: "memory");

    f16x8 xa[8];   // persistent prefetch regs (out0 rows of block tb+1)
    for (int tb = 0; tb < NB; ++tb) {
      const int buf = tb & 1;
      if (tb + 1 < NB) {
        WAIT_FLAG(tb + 2);           // out0 block tb+1 fully written + visible
        const _Float16* arow =
            out0 + ((size_t)((tb + 1) * 16 + l15) * BATCH + b) * DIM + q * 8;
#pragma unroll
        for (int kc = 0; kc < 8; kc++) xa[kc] = *(const f16x8*)(arow + kc * 32);
      }
      // ---- 16 recurrence steps for block tb (xa loads fly underneath) ----
#pragma unroll
      for (int ts = 0; ts < 16; ++ts) {
        const int t = tb * 16 + ts;
        const int p = ts & 1;
        const _Float16* xr = &xbuf[buf][ts][0];
        const float xh0 = (float)xr[c0],       xh1 = (float)xr[c1];
        const float xt0 = (float)xr[c0 + 256], xt1 = (float)xr[c1 + 256];

        f32x4 a0 = {0.f, 0.f, 0.f, 0.f}, a1 = a0, a2 = a0, a3 = a0;
        const _Float16* hb = &hbuf[p][q * 8];
#pragma unroll
        for (int kc = 0; kc < 8; kc++) {
          f16x8 a = *(const f16x8*)(hb + kc * 32);
          a0 = __builtin_amdgcn_mfma_f32_16x16x32_f16(a, Bh[0][kc], a0, 0, 0, 0);
          a1 = __builtin_amdgcn_mfma_f32_16x16x32_f16(a, Bh[1][kc], a1, 0, 0, 0);
          a2 = __builtin_amdgcn_mfma_f32_16x16x32_f16(a, Bt[0][kc], a2, 0, 0, 0);
          a3 = __builtin_amdgcn_mfma_f32_16x16x32_f16(a, Bt[1][kc], a3, 0, 0, 0);
        }
        const bool live = t < len;
        gate_update(a0[0] + xh0, a2[0] + xt0, live, h0);
        gate_update(a1[0] + xh1, a3[0] + xt1, live, h1);
        if (q == 0) {
          hbuf[1 - p][c0] = (_Float16)h0;
          hbuf[1 - p][c1] = (_Float16)h1;
          size_t o = ((size_t)t * BATCH + b) * DIM;
          out1[o + c0] = h0; out1[o + c1] = h1;
        }
        asm volatile("s_waitcnt lgkmcnt(0)\n\ts_barrier" ::: "memory");
      }
      // ---- dense x-GEMM for block tb+1 (regs ready; pure MFMA) ----
      if (tb + 1 < NB) {
        XGEMM(xa, 1 - buf);
        asm volatile("s_waitcnt lgkmcnt(0)\n\ts_barrier" ::: "memory");
      }
    }
#undef XGEMM
#undef WAIT_FLAG
    if (q == 0) {
      hn[BATCH * DIM + b * DIM + c0] = h0;
      hn[BATCH * DIM + b * DIM + c1] = h1;
    }
  }
}

extern "C" void kernel_launch(void* const* d_in, const int* in_sizes, int n_in,
                              void* d_out, int out_size, void* d_ws, size_t ws_size,
                              hipStream_t stream) {
  const float* input_ = (const float*)d_in[0];
  const void*  lenp   = d_in[1];
  const float* Wih0   = (const float*)d_in[2];
  const float* Whh0   = (const float*)d_in[3];
  const float* b0     = (const float*)d_in[4];
  const float* Wih1   = (const float*)d_in[5];
  const float* Whh1   = (const float*)d_in[6];
  const float* b1     = (const float*)d_in[7];
  float* out = (float*)d_out;
  char*  ws  = (char*)d_ws;

  _Float16* XW    = (_Float16*)(ws + XW_OFF);
  _Float16* Abuf  = (_Float16*)(ws + A_OFF);
  _Float16* blobs = (_Float16*)(ws + BLOB_OFF);   // [Wih0, Wih1, Whh0, Whh1]
  int*      flags = (int*)(ws + FLAG_OFF);
  float* hn = out + M_ROWS * DIM;                 // d_out tail: h_n [2][32][256]

  cvt_f32_to_f16<<<16384, 256, 0, stream>>>(input_, Abuf, (int)(M_ROWS * DIM / 4), flags);
  prep_blobs4<<<2048, 256, 0, stream>>>(Wih0, Wih1, Whh0, Whh1, blobs);
  gemm_xw<<<2048, 256, 0, stream>>>(Abuf, blobs + 0 * BLOB_ELT, b0, XW);
  recur_fused<<<2 * BATCH, 512, 0, stream>>>(XW,
                                             blobs + 2 * BLOB_ELT,   // Whh0 blob
                                             blobs + 3 * BLOB_ELT,   // Whh1 blob
                                             blobs + 1 * BLOB_ELT,   // Wih1 blob
                                             b1, lenp, Abuf, out, hn, flags);
}

// Round 6
// 2362.747 us; speedup vs baseline: 1.8389x; 1.0560x over previous
//
#include <hip/hip_runtime.h>
#include <cstdint>
#include <cstddef>

static constexpr int T_STEPS = 2048;
static constexpr int BATCH   = 32;
static constexpr int DIM     = 256;
static constexpr int NCOL    = 512;
static constexpr size_t M_ROWS = (size_t)T_STEPS * BATCH;   // 65536

typedef _Float16 f16x4 __attribute__((ext_vector_type(4)));
typedef _Float16 f16x8 __attribute__((ext_vector_type(8)));
typedef float    f32x4 __attribute__((ext_vector_type(4)));
struct alignas(8) H4 { _Float16 x, y, z, w; };

// ---- workspace layout (bytes) ----
static constexpr size_t XW_OFF   = 0;                           // XW f16 [65536][512] (bias folded) = 64 MB
static constexpr size_t A_OFF    = M_ROWS * NCOL * 2;           // Abuf f16 [65536][256] = 32 MB
static constexpr size_t BLOB_OFF = A_OFF + M_ROWS * DIM * 2;    // 4 blobs x 256 KB
static constexpr size_t BLOB_ELT = (size_t)DIM * NCOL;          // 131072 f16 per blob
static constexpr size_t FLAG_OFF = BLOB_OFF + 4 * BLOB_ELT * 2; // int[32] progress flags

// ---------------- prep: f32 -> f16 convert (input) + flag zero ----------------
__global__ void cvt_f32_to_f16(const float* __restrict__ src, _Float16* __restrict__ dst,
                               int n4, int* __restrict__ flags) {
  if (blockIdx.x == 0 && threadIdx.x < BATCH) flags[threadIdx.x] = 0;
  int i = blockIdx.x * blockDim.x + threadIdx.x;
  if (i >= n4) return;
  float4 v = ((const float4*)src)[i];
  H4 o; o.x = (_Float16)v.x; o.y = (_Float16)v.y; o.z = (_Float16)v.z; o.w = (_Float16)v.w;
  ((H4*)dst)[i] = o;
}

// ---------------- prep: W -> MFMA B-fragment blobs (cols 0:512 of [256][768]) ----
// blob[tn][kc][lane][j] = W[kc*32 + (lane>>4)*8 + j][tn*16 + (lane&15)]
__global__ void prep_blobs4(const float* __restrict__ w0, const float* __restrict__ w1,
                            const float* __restrict__ w2, const float* __restrict__ w3,
                            _Float16* __restrict__ blobs) {
  int gid = blockIdx.x * blockDim.x + threadIdx.x;   // < 4*131072
  int mat = gid >> 17;
  int rem = gid & 131071;
  int k = rem >> 9;        // 0..255
  int n = rem & 511;       // 0..511
  const float* src = (mat == 0) ? w0 : (mat == 1) ? w1 : (mat == 2) ? w2 : w3;
  float v = src[k * 768 + n];
  int kc = k >> 5, q = (k >> 3) & 3, j = k & 7, tn = n >> 4;
  int lane = (n & 15) + 16 * q;
  blobs[(size_t)mat * BLOB_ELT + ((size_t)(tn * 8 + kc) * 64 + lane) * 8 + j] = (_Float16)v;
}

// ---------------- GEMM: XW = A[65536,256] @ B[256,512] + bias, row-major f16 ----
__global__ __launch_bounds__(256) void gemm_xw(const _Float16* __restrict__ A,
                                               const _Float16* __restrict__ blob,
                                               const float* __restrict__ bias,
                                               _Float16* __restrict__ XW) {
  int lane = threadIdx.x & 63;
  int wave = threadIdx.x >> 6;
  int wid  = blockIdx.x * 4 + wave;       // 0..8191
  int mbase = (wid >> 1) * 16;
  int nhalf = wid & 1;
  int q = lane >> 4, n15 = lane & 15;

  f32x4 acc[16];
#pragma unroll
  for (int i = 0; i < 16; i++) acc[i] = (f32x4){0.f, 0.f, 0.f, 0.f};

  const _Float16* Arow = A + (size_t)(mbase + n15) * DIM + q * 8;
#pragma unroll
  for (int kc = 0; kc < 8; kc++) {
    f16x8 af = *(const f16x8*)(Arow + kc * 32);
#pragma unroll
    for (int nt = 0; nt < 16; nt++) {
      const _Float16* bp = blob + ((size_t)((nhalf * 16 + nt) * 8 + kc) * 64 + lane) * 8;
      f16x8 bf = *(const f16x8*)bp;
      acc[nt] = __builtin_amdgcn_mfma_f32_16x16x32_f16(af, bf, acc[nt], 0, 0, 0);
    }
  }
#pragma unroll
  for (int nt = 0; nt < 16; nt++) {
    int col = nhalf * 256 + nt * 16 + n15;
    float bv = bias[col];
#pragma unroll
    for (int r = 0; r < 4; r++) {
      int m = mbase + q * 4 + r;
      XW[(size_t)m * NCOL + col] = (_Float16)(acc[nt][r] + bv);
    }
  }
}

// ---------------- fused two-layer recurrence (producer/consumer pipeline) ----------------
__device__ __forceinline__ int read_len(const void* p, int b) {
  const long long* q = (const long long*)p;
  bool ok64 = true;
  for (int i = 0; i < 32; i++) { long long v = q[i]; if (v < 0 || v > 2048) ok64 = false; }
  return ok64 ? (int)q[b] : ((const int*)p)[b];
}

// async global->LDS staging: 64 lanes x 16B, LDS dest = uniform base + lane*16,
// global src per-lane.
__device__ __forceinline__ void gload_lds_row(const _Float16* g, _Float16* l) {
  __builtin_amdgcn_global_load_lds(
      (const __attribute__((address_space(1))) void*)g,
      (__attribute__((address_space(3))) void*)l, 16, 0, 0);
}

// Shared per-step epilogue math (bug-faithful gate computation).
__device__ __forceinline__ void gate_update(float pre_h, float pre_t, bool live, float& h) {
  const float K1 = 1.442695040888963f, K2 = 2.885390081777927f;
  float phc = fminf(fmaxf(pre_h, -20.f), 20.f);
  float e1 = __builtin_amdgcn_exp2f(-K2 * phc);
  float e2 = __builtin_amdgcn_exp2f(-K1 * pre_t);
  float u1 = 1.f + e1;
  float rr = __builtin_amdgcn_rcpf(u1 * (1.f + e2));
  float ttg = (1.f - e1) * rr;
  float tg  = u1 * rr;
  float cg = 0.5f + tg * (0.250905f + tg * (-0.00432f + tg * (-0.015525f)));
  float s = ttg + h * cg;
  h = live ? s : h;
}

// 64 WGs, 512 threads each.
//  * WG b in [0,32): PRODUCER = layer-0 recurrence (round-2 verified structure)
//    + per-block agent-scope RELEASE of flags[b].
//  * WG 32+b: CONSUMER = layer-1. Pipeline made COMPILER-PROOF this round:
//    out0 block tb+1 is staged via global_load_lds into obuf (fire-and-forget,
//    no VGPR liveness for LLVM to sink/spill -- round-5's register prefetch was
//    defeated exactly that way). Issue at block start, wait with the block-end
//    vmcnt(0), consume from LDS in the dense x-GEMM after the 16 steps.
//    obuf uses rule-21 XOR swizzle: linear LDS dest + inverse-swizzled global
//    SOURCE + same-XOR read => ds_read_b128 ~2-way instead of 16-way conflicts.
__global__ __launch_bounds__(512, 2) void recur_fused(const _Float16* __restrict__ xw0,
                                                      const _Float16* __restrict__ bwhh0,
                                                      const _Float16* __restrict__ bwhh1,
                                                      const _Float16* __restrict__ bwih1,
                                                      const float* __restrict__ b1,
                                                      const void* __restrict__ lenp,
                                                      _Float16* __restrict__ out0,
                                                      float* __restrict__ out1,
                                                      float* __restrict__ hn,
                                                      int* __restrict__ flags) {
  const int bid  = blockIdx.x;
  const int tid  = threadIdx.x;
  const int w    = tid >> 6;               // wave 0..7
  const int lane = tid & 63;
  const int q = lane >> 4, l15 = lane & 15;

  __shared__ __align__(16) _Float16 hbuf[2][DIM];        // ping-pong h (1 KB)
  __shared__ __align__(16) _Float16 xbuf[2][16][NCOL];   // xw blocks (32 KB)
  __shared__ __align__(16) _Float16 obuf[2][16][DIM];    // staged out0 blocks (16 KB)

  const int c0 = (2 * w) * 16 + l15;
  const int c1 = (2 * w + 1) * 16 + l15;
  constexpr int NB = T_STEPS / 16;

  if (bid < BATCH) {
    // ================= PRODUCER: layer 0 =================
    const int b = bid;
    const int len = read_len(lenp, b);
    f16x8 Bh[2][8], Bt[2][8];
#pragma unroll
    for (int pp = 0; pp < 2; pp++)
#pragma unroll
      for (int kc = 0; kc < 8; kc++) {
        Bh[pp][kc] = *(const f16x8*)(bwhh0 + ((size_t)((2 * w + pp) * 8 + kc) * 64 + lane) * 8);
        Bt[pp][kc] = *(const f16x8*)(bwhh0 + ((size_t)((16 + 2 * w + pp) * 8 + kc) * 64 + lane) * 8);
      }
    if (tid < DIM) hbuf[0][tid] = (_Float16)0.f;

    const _Float16* xrow = xw0 + (size_t)b * NCOL;
    const size_t xstride = (size_t)BATCH * NCOL;

    gload_lds_row(xrow + (size_t)(2 * w)     * xstride + lane * 8, &xbuf[0][2 * w][0]);
    gload_lds_row(xrow + (size_t)(2 * w + 1) * xstride + lane * 8, &xbuf[0][2 * w + 1][0]);
    asm volatile("s_waitcnt vmcnt(0)" ::: "memory");
    __syncthreads();

    float h0 = 0.f, h1 = 0.f;
    for (int tb = 0; tb < NB; ++tb) {
      const int buf = tb & 1;
      if (tb + 1 < NB) {
        const _Float16* gsrc = xrow + (size_t)((tb + 1) * 16) * xstride;
        gload_lds_row(gsrc + (size_t)(2 * w)     * xstride + lane * 8, &xbuf[1 - buf][2 * w][0]);
        gload_lds_row(gsrc + (size_t)(2 * w + 1) * xstride + lane * 8, &xbuf[1 - buf][2 * w + 1][0]);
      }
#pragma unroll
      for (int ts = 0; ts < 16; ++ts) {
        const int t = tb * 16 + ts;
        const int p = ts & 1;
        const _Float16* xr = &xbuf[buf][ts][0];
        const float xh0 = (float)xr[c0],       xh1 = (float)xr[c1];
        const float xt0 = (float)xr[c0 + 256], xt1 = (float)xr[c1 + 256];

        f32x4 a0 = {0.f, 0.f, 0.f, 0.f}, a1 = a0, a2 = a0, a3 = a0;
        const _Float16* hb = &hbuf[p][q * 8];
#pragma unroll
        for (int kc = 0; kc < 8; kc++) {
          f16x8 a = *(const f16x8*)(hb + kc * 32);
          a0 = __builtin_amdgcn_mfma_f32_16x16x32_f16(a, Bh[0][kc], a0, 0, 0, 0);
          a1 = __builtin_amdgcn_mfma_f32_16x16x32_f16(a, Bh[1][kc], a1, 0, 0, 0);
          a2 = __builtin_amdgcn_mfma_f32_16x16x32_f16(a, Bt[0][kc], a2, 0, 0, 0);
          a3 = __builtin_amdgcn_mfma_f32_16x16x32_f16(a, Bt[1][kc], a3, 0, 0, 0);
        }
        const bool live = t < len;
        gate_update(a0[0] + xh0, a2[0] + xt0, live, h0);
        gate_update(a1[0] + xh1, a3[0] + xt1, live, h1);
        _Float16 s0 = (_Float16)h0, s1 = (_Float16)h1;
        if (q == 0) {
          hbuf[1 - p][c0] = s0;
          hbuf[1 - p][c1] = s1;
          size_t o = ((size_t)t * BATCH + b) * DIM;
          out0[o + c0] = s0; out0[o + c1] = s1;
        }
        if (ts == 15) {
          asm volatile("s_waitcnt vmcnt(0) lgkmcnt(0)\n\ts_barrier" ::: "memory");
        } else {
          asm volatile("s_waitcnt lgkmcnt(0)\n\ts_barrier" ::: "memory");
        }
      }
      if (tid == 0)
        __hip_atomic_store(&flags[b], tb + 1, __ATOMIC_RELEASE, __HIP_MEMORY_SCOPE_AGENT);
    }
    if (q == 0) {
      hn[b * DIM + c0] = h0;
      hn[b * DIM + c1] = h1;
    }
  } else {
    // ================= CONSUMER: layer 1 (LDS-staged pipeline) =================
    const int b = bid - BATCH;
    const int len = read_len(lenp, b);
    f16x8 Bh[2][8], Bt[2][8];
#pragma unroll
    for (int pp = 0; pp < 2; pp++)
#pragma unroll
      for (int kc = 0; kc < 8; kc++) {
        Bh[pp][kc] = *(const f16x8*)(bwhh1 + ((size_t)((2 * w + pp) * 8 + kc) * 64 + lane) * 8);
        Bt[pp][kc] = *(const f16x8*)(bwhh1 + ((size_t)((16 + 2 * w + pp) * 8 + kc) * 64 + lane) * 8);
      }
    const float bb0 = b1[c0], bb1 = b1[c1], bb2 = b1[c0 + 256], bb3 = b1[c1 + 256];
    if (tid < DIM) hbuf[0][tid] = (_Float16)0.f;
    __syncthreads();

#define WAIT_FLAG(TH_)                                                                   \
    {                                                                                    \
      int it = 0;                                                                        \
      while (__hip_atomic_load(&flags[b], __ATOMIC_RELAXED, __HIP_MEMORY_SCOPE_AGENT)    \
             < (TH_)) {                                                                  \
        __builtin_amdgcn_s_sleep(2);                                                     \
        if (++it > (1 << 22)) break;   /* hang-breaker: fail loud, not forever */        \
      }                                                                                  \
      (void)__hip_atomic_load(&flags[b], __ATOMIC_ACQUIRE, __HIP_MEMORY_SCOPE_AGENT);    \
    }

    // Stage out0 block TB_ (16 rows x 512B) into obuf[NB_].
    // Wave w stages rows {2w, 2w+1} with ONE 64-lane call: lanes 0-31 -> row 2w,
    // lanes 32-63 -> row 2w+1 (LDS = uniform base + lane*16 covers both rows
    // contiguously). Source is inverse-XOR-swizzled so the read side's
    // off ^ ((row&7)<<4) lands on the right data (rule 21).
#define STAGE_OBUF(TB_, NB_)                                                             \
    {                                                                                    \
      const int r_   = 2 * w + (lane >> 5);                                              \
      const int offl = (lane & 31) * 16;                                                 \
      const int goff = offl ^ ((r_ & 7) << 4);                                           \
      const _Float16* g_ =                                                               \
          out0 + ((size_t)((TB_) * 16 + r_) * BATCH + b) * DIM + (goff >> 1);            \
      gload_lds_row(g_, &obuf[NB_][2 * w][0]);                                           \
    }

    // Dense x-GEMM: xw1[16 steps][my 64 cols] = obuf-block @ Wih1 + b1.
    // A-frags from swizzled obuf (ds_read_b128, ~2-way banks); B-frags from
    // global blob (L2/L3); pure MFMA; writes xbuf[DST_].
#define XGEMM_OBUF(NB_, DST_)                                                            \
    {                                                                                    \
      f16x8 xa_[8];                                                                      \
      _Pragma("unroll")                                                                  \
      for (int kc = 0; kc < 8; kc++) {                                                   \
        const int off_ = (q * 16 + kc * 64) ^ ((l15 & 7) << 4);                          \
        xa_[kc] = *(const f16x8*)((const char*)(&obuf[NB_][0][0]) + l15 * 512 + off_);   \
      }                                                                                  \
      _Pragma("unroll")                                                                  \
      for (int ti = 0; ti < 4; ti++) {                                                   \
        const int tn = (ti < 2) ? (2 * w + ti) : (16 + 2 * w + (ti - 2));                \
        f32x4 acc = {0.f, 0.f, 0.f, 0.f};                                                \
        _Pragma("unroll")                                                                \
        for (int kc = 0; kc < 8; kc++) {                                                 \
          f16x8 bf = *(const f16x8*)(bwih1 + ((size_t)(tn * 8 + kc) * 64 + lane) * 8);   \
          acc = __builtin_amdgcn_mfma_f32_16x16x32_f16(xa_[kc], bf, acc, 0, 0, 0);       \
        }                                                                                \
        const int   col = (ti == 0) ? c0 : (ti == 1) ? c1 : (ti == 2) ? (c0 + 256)       \
                                                                      : (c1 + 256);     \
        const float bv  = (ti == 0) ? bb0 : (ti == 1) ? bb1 : (ti == 2) ? bb2 : bb3;     \
        _Pragma("unroll")                                                                \
        for (int r2 = 0; r2 < 4; r2++)                                                   \
          xbuf[DST_][q * 4 + r2][col] = (_Float16)(acc[r2] + bv);                        \
      }                                                                                  \
    }

    float h0 = 0.f, h1 = 0.f;

    // prologue: stage + x-GEMM for block 0 (serial once)
    WAIT_FLAG(1);
    STAGE_OBUF(0, 0);
    asm volatile("s_waitcnt vmcnt(0)" ::: "memory");
    __syncthreads();
    XGEMM_OBUF(0, 0);
    asm volatile("s_waitcnt lgkmcnt(0)\n\ts_barrier" ::: "memory");

    for (int tb = 0; tb < NB; ++tb) {
      const int buf = tb & 1;
      if (tb + 1 < NB) {
        WAIT_FLAG(tb + 2);            // out0 block tb+1 written + LLC-visible
        STAGE_OBUF(tb + 1, 1 - buf);  // fire-and-forget; waited at ts==15
      }
      // ---- 16 recurrence steps for block tb (staging flies underneath) ----
#pragma unroll
      for (int ts = 0; ts < 16; ++ts) {
        const int t = tb * 16 + ts;
        const int p = ts & 1;
        const _Float16* xr = &xbuf[buf][ts][0];
        const float xh0 = (float)xr[c0],       xh1 = (float)xr[c1];
        const float xt0 = (float)xr[c0 + 256], xt1 = (float)xr[c1 + 256];

        f32x4 a0 = {0.f, 0.f, 0.f, 0.f}, a1 = a0, a2 = a0, a3 = a0;
        const _Float16* hb = &hbuf[p][q * 8];
#pragma unroll
        for (int kc = 0; kc < 8; kc++) {
          f16x8 a = *(const f16x8*)(hb + kc * 32);
          a0 = __builtin_amdgcn_mfma_f32_16x16x32_f16(a, Bh[0][kc], a0, 0, 0, 0);
          a1 = __builtin_amdgcn_mfma_f32_16x16x32_f16(a, Bh[1][kc], a1, 0, 0, 0);
          a2 = __builtin_amdgcn_mfma_f32_16x16x32_f16(a, Bt[0][kc], a2, 0, 0, 0);
          a3 = __builtin_amdgcn_mfma_f32_16x16x32_f16(a, Bt[1][kc], a3, 0, 0, 0);
        }
        const bool live = t < len;
        gate_update(a0[0] + xh0, a2[0] + xt0, live, h0);
        gate_update(a1[0] + xh1, a3[0] + xt1, live, h1);
        if (q == 0) {
          hbuf[1 - p][c0] = (_Float16)h0;
          hbuf[1 - p][c1] = (_Float16)h1;
          size_t o = ((size_t)t * BATCH + b) * DIM;
          out1[o + c0] = h0; out1[o + c1] = h1;
        }
        if (ts == 15) {
          // staging for block tb+1 (issued 16 steps ago) must be in LDS now;
          // out1 stores drain too -- once per block, like the producer.
          asm volatile("s_waitcnt vmcnt(0) lgkmcnt(0)\n\ts_barrier" ::: "memory");
        } else {
          asm volatile("s_waitcnt lgkmcnt(0)\n\ts_barrier" ::: "memory");
        }
      }
      // ---- dense x-GEMM for block tb+1 (A from LDS; pure compute) ----
      if (tb + 1 < NB) {
        XGEMM_OBUF(1 - buf, 1 - buf);
        asm volatile("s_waitcnt lgkmcnt(0)\n\ts_barrier" ::: "memory");
      }
    }
#undef XGEMM_OBUF
#undef STAGE_OBUF
#undef WAIT_FLAG
    if (q == 0) {
      hn[BATCH * DIM + b * DIM + c0] = h0;
      hn[BATCH * DIM + b * DIM + c1] = h1;
    }
  }
}

extern "C" void kernel_launch(void* const* d_in, const int* in_sizes, int n_in,
                              void* d_out, int out_size, void* d_ws, size_t ws_size,
                              hipStream_t stream) {
  const float* input_ = (const float*)d_in[0];
  const void*  lenp   = d_in[1];
  const float* Wih0   = (const float*)d_in[2];
  const float* Whh0   = (const float*)d_in[3];
  const float* b0     = (const float*)d_in[4];
  const float* Wih1   = (const float*)d_in[5];
  const float* Whh1   = (const float*)d_in[6];
  const float* b1     = (const float*)d_in[7];
  float* out = (float*)d_out;
  char*  ws  = (char*)d_ws;

  _Float16* XW    = (_Float16*)(ws + XW_OFF);
  _Float16* Abuf  = (_Float16*)(ws + A_OFF);
  _Float16* blobs = (_Float16*)(ws + BLOB_OFF);   // [Wih0, Wih1, Whh0, Whh1]
  int*      flags = (int*)(ws + FLAG_OFF);
  float* hn = out + M_ROWS * DIM;                 // d_out tail: h_n [2][32][256]

  cvt_f32_to_f16<<<16384, 256, 0, stream>>>(input_, Abuf, (int)(M_ROWS * DIM / 4), flags);
  prep_blobs4<<<2048, 256, 0, stream>>>(Wih0, Wih1, Whh0, Whh1, blobs);
  gemm_xw<<<2048, 256, 0, stream>>>(Abuf, blobs + 0 * BLOB_ELT, b0, XW);
  recur_fused<<<2 * BATCH, 512, 0, stream>>>(XW,
                                             blobs + 2 * BLOB_ELT,   // Whh0 blob
                                             blobs + 3 * BLOB_ELT,   // Whh1 blob
                                             blobs + 1 * BLOB_ELT,   // Wih1 blob
                                             b1, lenp, Abuf, out, hn, flags);
}